// Round 10
// baseline (16465.651 us; speedup 1.0000x reference)
//
#include <hip/hip_runtime.h>
#include <hip/hip_fp16.h>

// ---------------------------------------------------------------------------
// 2-layer LSTM (B=256, T=256, D=128, H=1024) + final Linear(H->128).
// Persistent kernel, one phase per timestep, device-scope grid barrier.
// fp16 MFMA (16x16x32), fp32 accumulation/elementwise. Weights in LDS.
//
// R10: NO CACHE INVALIDATION. h-state reads are relaxed agent-scope atomic
// loads (sc0+sc1 -> bypass L1+L2, read coherence point directly); h-writes
// remain relaxed agent write-through stores. With both sides at the
// coherence point, no stale copy can exist -> the per-phase acquire fence
// (buffer_inv of L1+L2) is REMOVED. xh/weights/biases stay cache-resident
// across phases (never invalidated). Barrier = R9's flag array, minus fence.
// ---------------------------------------------------------------------------

#define Bq 256
#define Hq 1024

typedef _Float16 half8 __attribute__((ext_vector_type(8)));
typedef float    floatx4 __attribute__((ext_vector_type(4)));

#define N_W1 8388608LL   // 128 cb * 65536  ([ks64][kb4][n2][jj16][e8])
#define N_W0 4718592LL   // 128 cb * 36864  ([ks36][kb4][n2][jj16][e8])
#define N_XH 8388608LL   // T*B*D
#define N_H  262144LL    // B*H
#define BH   262144

// ws byte offsets
#define OFF_W1 0LL
#define OFF_W0 16777216LL
#define OFF_XH 26214400LL
#define OFF_BA 42991616LL
#define OFF_BB 44040192LL
#define OFF_HF 45088768LL
#define OFF_SY 46137344LL
#define REQ_WS 46139392LL   // OFF_SY + 2048

// ---------------------------------------------------------------------------
__global__ void ws_sentinel_kernel(float* __restrict__ out, int n, float v)
{
    int i = blockIdx.x * blockDim.x + threadIdx.x;
    if (i < n) out[i] = v;
}

// ---------------------------------------------------------------------------
__global__ void prep_kernel(const float* __restrict__ x, const float* __restrict__ h0,
                            const float* __restrict__ Wih0, const float* __restrict__ Whh0,
                            const float* __restrict__ Wih1, const float* __restrict__ Whh1,
                            _Float16* __restrict__ w1p, _Float16* __restrict__ w0p,
                            _Float16* __restrict__ xh,
                            _Float16* __restrict__ bufA, _Float16* __restrict__ bufB,
                            unsigned* __restrict__ sync)
{
    long long gid = (long long)blockIdx.x * blockDim.x + threadIdx.x;
    if (gid < 512) sync[gid] = 0u;   // 256 arrival flags (monotonic) + spare

    if (gid < N_W1) {
        // [cb][ks][kb][n][jj][e]; gate-col row = (2n + jj>>3)*1024 + cb*8 + (jj&7)
        long long i = gid;
        int e  = (int)(i & 7);
        int jj = (int)((i >> 3) & 15);
        int n  = (int)((i >> 7) & 1);
        int kb = (int)((i >> 8) & 3);
        int ks = (int)((i >> 10) & 63);
        int cb = (int)(i >> 16);
        int row = (2 * n + (jj >> 3)) * 1024 + cb * 8 + (jj & 7);
        int k = ks * 32 + kb * 8 + e;
        float v = (k < 1024) ? Wih1[(size_t)row * 1024 + k]
                             : Whh1[(size_t)row * 1024 + (k - 1024)];
        w1p[i] = (_Float16)v;
    } else if (gid < N_W1 + N_W0) {
        long long i = gid - N_W1;
        int cb = (int)(i / 36864LL);
        int r  = (int)(i - (long long)cb * 36864LL);
        int ks = r >> 10;
        int kb = (r >> 8) & 3;
        int n  = (r >> 7) & 1;
        int jj = (r >> 3) & 15;
        int e  = r & 7;
        int row = (2 * n + (jj >> 3)) * 1024 + cb * 8 + (jj & 7);
        int k = ks * 32 + kb * 8 + e;
        float v = (k < 128) ? Wih0[(size_t)row * 128 + k]
                            : Whh0[(size_t)row * 1024 + (k - 128)];
        w0p[i] = (_Float16)v;
    } else if (gid < N_W1 + N_W0 + N_XH) {
        long long i = gid - N_W1 - N_W0;
        // xh[t][b][d] = x[b][t][d]
        int d = (int)(i & 127);
        int b = (int)((i >> 7) & 255);
        int t = (int)(i >> 15);
        xh[i] = (_Float16)x[((size_t)b * 256 + t) * 128 + d];
    } else if (gid < N_W1 + N_W0 + N_XH + N_H) {
        long long i = gid - N_W1 - N_W0 - N_XH;
        _Float16 v = (_Float16)h0[i];
        bufA[BH + i] = v;   // h_a(-1) parity 1
        bufB[BH + i] = v;   // h_b(-1) parity 1
    }
}

// ---------------------------------------------------------------------------
// Flag-array grid barrier WITHOUT any cache fence. Correctness: all
// cross-block data is written AND read at the coherence point (relaxed
// agent-scope atomics), so no cache can hold a stale copy; the only
// ordering needed is store-completion (s_waitcnt 0) before flag publish.
__device__ __forceinline__ void gridbar(unsigned* flags, int bid, unsigned target)
{
    __builtin_amdgcn_s_waitcnt(0);     // own write-through stores at IF
    __syncthreads();                   // all waves of this block drained
    if (threadIdx.x == 0)
        __hip_atomic_store(flags + bid, target, __ATOMIC_RELAXED,
                           __HIP_MEMORY_SCOPE_AGENT);
    if (threadIdx.x < 256) {
        int guard = 0;
        while (__hip_atomic_load(flags + threadIdx.x, __ATOMIC_RELAXED,
                                 __HIP_MEMORY_SCOPE_AGENT) < target) {
            __builtin_amdgcn_s_sleep(1);
            if (++guard > (1 << 18)) break;        // safety: wrong, not wedged
        }
    }
    __syncthreads();
}

// 16B h-state load at the coherence point (bypasses L1+L2; no fence needed)
__device__ __forceinline__ half8 ldIF16(const _Float16* p)
{
    union { unsigned long long u[2]; half8 h; } cv;
    cv.u[0] = __hip_atomic_load((const unsigned long long*)p,
                                __ATOMIC_RELAXED, __HIP_MEMORY_SCOPE_AGENT);
    cv.u[1] = __hip_atomic_load((const unsigned long long*)p + 1,
                                __ATOMIC_RELAXED, __HIP_MEMORY_SCOPE_AGENT);
    return cv.h;
}

#define MFMA16(A, Bv, C) __builtin_amdgcn_mfma_f32_16x16x32_f16((A), (Bv), (C), 0, 0, 0)

// one k-step (K=32): 2 A-frags, 2 B-frags (LDS), 4 MFMAs
// KS1C: cached A-loads (read-only xh).  KS1IF: coherence-point A-loads (h).
#define KS1C(AP_, MF1OFF_) do {                                     \
    half8 a0 = *(const half8*)(AP_);                                \
    half8 a1 = *(const half8*)((AP_) + (MF1OFF_));                  \
    half8 b0 = *(const half8*)(bp);                                 \
    half8 b1 = *(const half8*)(bp + 128);                           \
    acc[0][0] = MFMA16(a0, b0, acc[0][0]);                          \
    acc[0][1] = MFMA16(a0, b1, acc[0][1]);                          \
    acc[1][0] = MFMA16(a1, b0, acc[1][0]);                          \
    acc[1][1] = MFMA16(a1, b1, acc[1][1]);                          \
} while (0)

#define KS1IF(AP_, MF1OFF_) do {                                    \
    half8 a0 = ldIF16(AP_);                                         \
    half8 a1 = ldIF16((AP_) + (MF1OFF_));                           \
    half8 b0 = *(const half8*)(bp);                                 \
    half8 b1 = *(const half8*)(bp + 128);                           \
    acc[0][0] = MFMA16(a0, b0, acc[0][0]);                          \
    acc[0][1] = MFMA16(a0, b1, acc[0][1]);                          \
    acc[1][0] = MFMA16(a1, b0, acc[1][0]);                          \
    acc[1][1] = MFMA16(a1, b1, acc[1][1]);                          \
} while (0)

__global__ void __launch_bounds__(512)
lstm_main(const _Float16* __restrict__ w1p, const _Float16* __restrict__ w0p,
          const _Float16* __restrict__ xh,
          _Float16* __restrict__ bufA, _Float16* __restrict__ bufB,
          float* __restrict__ hbF,
          const float* __restrict__ c0,
          const float* __restrict__ bih0, const float* __restrict__ bhh0,
          const float* __restrict__ bih1, const float* __restrict__ bhh1,
          const float* __restrict__ Wout, const float* __restrict__ bout,
          float* __restrict__ out, unsigned* __restrict__ sync)
{
    __shared__ _Float16 wlds[65536];   // 128 KiB

    const int tid  = threadIdx.x;
    const int lane = tid & 63;
    const int w    = tid >> 6;           // 0..7
    const int bid  = blockIdx.x;
    const int xcd  = bid & 7;
    const int slot = bid >> 3;           // 0..31
    const int isL1 = ((slot & 1) == 0);  // 16 L1 + 16 L0 blocks per XCD
    const int cb   = xcd * 16 + (slot >> 1);   // 0..127 column-block id
    const int jbase = cb * 8;
    const int jj = lane & 15;
    const int kb = lane >> 4;            // 0..3
    const int jh = jj & 7;
    const int lo = (jj < 8);
    const int rowbase = w * 32;          // wave's 32 batch rows

    // ---- load this block's weights into LDS (once) ----
    {
        const _Float16* src = isL1 ? (w1p + (size_t)cb * 65536)
                                   : (w0p + (size_t)cb * 36864);
        const int nch = isL1 ? 8192 : 4608;   // 16B chunks
        for (int i = tid; i < nch; i += 512)
            *(half8*)&wlds[(size_t)i * 8] = *(const half8*)&src[(size_t)i * 8];
    }
    __syncthreads();

    // ---- biases + cell-state init ----
    const float* bi  = isL1 ? bih1 : bih0;
    const float* bhp = isL1 ? bhh1 : bhh0;
    float bias[4];
#pragma unroll
    for (int g = 0; g < 4; ++g)
        bias[g] = bi[g * 1024 + jbase + jh] + bhp[g * 1024 + jbase + jh];

    float cc[2][4];
#pragma unroll
    for (int mf = 0; mf < 2; ++mf)
#pragma unroll
        for (int r = 0; r < 4; ++r)
            cc[mf][r] = c0[(size_t)(rowbase + mf * 16 + kb * 4 + r) * Hq + jbase + jh];

    floatx4 acc[2][2];

    for (int t = -1; t <= 255; ++t) {
        const int active = isL1 ? (t >= 0) : (t < 255);
        if (active) {
#pragma unroll
            for (int mf = 0; mf < 2; ++mf)
#pragma unroll
                for (int n = 0; n < 2; ++n)
                    acc[mf][n] = (floatx4){0.f, 0.f, 0.f, 0.f};

            const _Float16* bp = wlds + kb * 256 + jj * 8;

            if (isL1) {
                // part 1: h_a(t)  (ks 0..31)
                const _Float16* ap = bufA + (size_t)(t & 1) * BH
                                   + (size_t)(rowbase + jj) * Hq + kb * 8;
#pragma unroll 4
                for (int ks = 0; ks < 32; ++ks) { KS1IF(ap, 16 * Hq); ap += 32; bp += 1024; }
                // part 2: h_b(t-1)  (ks 32..63)
                ap = bufB + (size_t)((t + 1) & 1) * BH
                   + (size_t)(rowbase + jj) * Hq + kb * 8;
#pragma unroll 4
                for (int ks = 0; ks < 32; ++ks) { KS1IF(ap, 16 * Hq); ap += 32; bp += 1024; }
            } else {
                // part 1: x(t+1)  (ks 0..3, K=128 rows) — read-only, cached
                const _Float16* ap = xh + (size_t)(t + 1) * (Bq * 128)
                                   + (size_t)(rowbase + jj) * 128 + kb * 8;
#pragma unroll
                for (int ks = 0; ks < 4; ++ks)  { KS1C(ap, 16 * 128); ap += 32; bp += 1024; }
                // part 2: h_a(t)  (ks 4..35)
                ap = bufA + (size_t)(t & 1) * BH
                   + (size_t)(rowbase + jj) * Hq + kb * 8;
#pragma unroll 4
                for (int ks = 0; ks < 32; ++ks) { KS1IF(ap, 16 * Hq); ap += 32; bp += 1024; }
            }

            // ---- elementwise: gate-pair exchange + cell update + h store ----
            // h stores: fp16 pairs packed to 4B words, RELAXED agent atomics
            // (write-through; matching agent-scope reads -> no fence needed).
            _Float16* hb = isL1 ? (bufB + (size_t)(t & 1) * BH)
                                : (bufA + (size_t)((t + 1) & 1) * BH);
            unsigned* hb32 = (unsigned*)hb;
#pragma unroll
            for (int mf = 0; mf < 2; ++mf) {
#pragma unroll
                for (int r = 0; r < 4; ++r) {
                    float o0 = acc[mf][0][r];       // lo: i, hi: f
                    float o1 = acc[mf][1][r];       // lo: g, hi: o
                    float p0 = __shfl_xor(o0, 8);
                    float p1 = __shfl_xor(o1, 8);
                    float gi = (lo ? o0 : p0) + bias[0];
                    float gf = (lo ? p0 : o0) + bias[1];
                    float gg = (lo ? o1 : p1) + bias[2];
                    float go = (lo ? p1 : o1) + bias[3];
                    float ii = 1.f / (1.f + expf(-gi));
                    float ff = 1.f / (1.f + expf(-gf));
                    float gt = tanhf(gg);
                    float oo = 1.f / (1.f + expf(-go));
                    float cn = ff * cc[mf][r] + ii * gt;
                    cc[mf][r] = cn;
                    float hn = oo * tanhf(cn);

                    union { _Float16 f; unsigned short u; } cv;
                    cv.f = (_Float16)hn;
                    int prt = __shfl_xor((int)cv.u, 1);   // neighbor j^1's bits
                    int row = rowbase + mf * 16 + kb * 4 + r;
                    if (lo && ((jh & 1) == 0)) {
                        unsigned word = (unsigned)cv.u | ((unsigned)prt << 16);
                        __hip_atomic_store(hb32 + (((size_t)row * Hq + jbase + jh) >> 1),
                                           word, __ATOMIC_RELAXED,
                                           __HIP_MEMORY_SCOPE_AGENT);
                    }
                    if (lo && isL1 && t == 255)
                        __hip_atomic_store(hbF + (size_t)row * Hq + jbase + jh,
                                           hn, __ATOMIC_RELAXED,
                                           __HIP_MEMORY_SCOPE_AGENT);
                }
            }
        }

        gridbar(sync, bid, (unsigned)(t + 2));
    }

    // ---- final: out[b][o] = b_out[o] + sum_k hbF[b][k] * Wout[o][k] ----
    // hbF written at coherence point this call; these lines were never read
    // before in this dispatch, and dispatch-start acquire invalidated stale
    // copies from prior replays -> plain cached reads are safe.
    int gid = bid * 512 + tid;
    if (gid < Bq * 128) {
        int b = gid >> 7, o = gid & 127;
        const floatx4* hr = (const floatx4*)(hbF + (size_t)b * Hq);
        const floatx4* wr = (const floatx4*)(Wout + (size_t)o * Hq);
        float s = bout[o];
#pragma unroll 4
        for (int k = 0; k < Hq / 4; ++k) {
            floatx4 hv = hr[k], wv = wr[k];
            s += hv[0] * wv[0] + hv[1] * wv[1] + hv[2] * wv[2] + hv[3] * wv[3];
        }
        out[gid] = s;
    }
}

// ---------------------------------------------------------------------------
extern "C" void kernel_launch(void* const* d_in, const int* in_sizes, int n_in,
                              void* d_out, int out_size, void* d_ws, size_t ws_size,
                              hipStream_t stream)
{
    (void)in_sizes; (void)n_in;
    float* out = (float*)d_out;

    if (ws_size < (size_t)REQ_WS) {
        float v = -(float)(ws_size >> 20);
        hipLaunchKernelGGL(ws_sentinel_kernel, dim3((out_size + 255) / 256), dim3(256),
                           0, stream, out, out_size, v);
        return;
    }

    const float* x    = (const float*)d_in[0];
    const float* h0   = (const float*)d_in[1];
    const float* c0   = (const float*)d_in[2];
    const float* Wih0 = (const float*)d_in[3];
    const float* Whh0 = (const float*)d_in[4];
    const float* bih0 = (const float*)d_in[5];
    const float* bhh0 = (const float*)d_in[6];
    const float* Wih1 = (const float*)d_in[7];
    const float* Whh1 = (const float*)d_in[8];
    const float* bih1 = (const float*)d_in[9];
    const float* bhh1 = (const float*)d_in[10];
    const float* Wout = (const float*)d_in[11];
    const float* bout = (const float*)d_in[12];

    char* ws = (char*)d_ws;
    _Float16* w1p  = (_Float16*)(ws + OFF_W1);
    _Float16* w0p  = (_Float16*)(ws + OFF_W0);
    _Float16* xh   = (_Float16*)(ws + OFF_XH);
    _Float16* bufA = (_Float16*)(ws + OFF_BA);
    _Float16* bufB = (_Float16*)(ws + OFF_BB);
    float*    hbF  = (float*)   (ws + OFF_HF);
    unsigned* sync = (unsigned*)(ws + OFF_SY);

    long long total = N_W1 + N_W0 + N_XH + N_H;   // 21,757,952 = 84992*256
    hipLaunchKernelGGL(prep_kernel, dim3((unsigned)(total / 256)), dim3(256), 0, stream,
                       x, h0, Wih0, Whh0, Wih1, Whh1, w1p, w0p, xh, bufA, bufB, sync);

    hipLaunchKernelGGL(lstm_main, dim3(256), dim3(512), 0, stream,
                       w1p, w0p, xh, bufA, bufB, hbF, c0,
                       bih0, bhh0, bih1, bhh1, Wout, bout, out, sync);
}

// Round 11
// 9888.648 us; speedup vs baseline: 1.6651x; 1.6651x over previous
//
#include <hip/hip_runtime.h>
#include <hip/hip_fp16.h>

// ---------------------------------------------------------------------------
// 2-layer LSTM (B=256, T=256, D=128, H=1024) + final Linear(H->128).
// Persistent kernel, one phase per timestep, flag-array grid barrier +
// per-phase acquire fence (R9 data plane, unchanged).
// R11: DEEP CHUNKED PREFETCH. K-loop restructured into 8-step chunks with
// double-buffered fragment registers: 16 independent 16B loads issued for
// chunk c+1 while chunk c feeds MFMAs -> ~16 loads in flight per wave
// (vs ~2-4), attacking the measured HBM/IF-latency serialization
// (6.7 MB/phase moving at only 166 GB/s = ~2.5 lines in flight per CU).
// ---------------------------------------------------------------------------

#define Bq 256
#define Hq 1024

typedef _Float16 half8 __attribute__((ext_vector_type(8)));
typedef float    floatx4 __attribute__((ext_vector_type(4)));

#define N_W1 8388608LL   // 128 cb * 65536  ([ks64][kb4][n2][jj16][e8])
#define N_W0 4718592LL   // 128 cb * 36864  ([ks36][kb4][n2][jj16][e8])
#define N_XH 8388608LL   // T*B*D
#define N_H  262144LL    // B*H
#define BH   262144

// ws byte offsets
#define OFF_W1 0LL
#define OFF_W0 16777216LL
#define OFF_XH 26214400LL
#define OFF_BA 42991616LL
#define OFF_BB 44040192LL
#define OFF_HF 45088768LL
#define OFF_SY 46137344LL
#define REQ_WS 46139392LL   // OFF_SY + 2048

// ---------------------------------------------------------------------------
__global__ void ws_sentinel_kernel(float* __restrict__ out, int n, float v)
{
    int i = blockIdx.x * blockDim.x + threadIdx.x;
    if (i < n) out[i] = v;
}

// ---------------------------------------------------------------------------
__global__ void prep_kernel(const float* __restrict__ x, const float* __restrict__ h0,
                            const float* __restrict__ Wih0, const float* __restrict__ Whh0,
                            const float* __restrict__ Wih1, const float* __restrict__ Whh1,
                            _Float16* __restrict__ w1p, _Float16* __restrict__ w0p,
                            _Float16* __restrict__ xh,
                            _Float16* __restrict__ bufA, _Float16* __restrict__ bufB,
                            unsigned* __restrict__ sync)
{
    long long gid = (long long)blockIdx.x * blockDim.x + threadIdx.x;
    if (gid < 512) sync[gid] = 0u;   // 256 arrival flags (monotonic) + spare

    if (gid < N_W1) {
        // [cb][ks][kb][n][jj][e]; gate-col row = (2n + jj>>3)*1024 + cb*8 + (jj&7)
        long long i = gid;
        int e  = (int)(i & 7);
        int jj = (int)((i >> 3) & 15);
        int n  = (int)((i >> 7) & 1);
        int kb = (int)((i >> 8) & 3);
        int ks = (int)((i >> 10) & 63);
        int cb = (int)(i >> 16);
        int row = (2 * n + (jj >> 3)) * 1024 + cb * 8 + (jj & 7);
        int k = ks * 32 + kb * 8 + e;
        float v = (k < 1024) ? Wih1[(size_t)row * 1024 + k]
                             : Whh1[(size_t)row * 1024 + (k - 1024)];
        w1p[i] = (_Float16)v;
    } else if (gid < N_W1 + N_W0) {
        long long i = gid - N_W1;
        int cb = (int)(i / 36864LL);
        int r  = (int)(i - (long long)cb * 36864LL);
        int ks = r >> 10;
        int kb = (r >> 8) & 3;
        int n  = (r >> 7) & 1;
        int jj = (r >> 3) & 15;
        int e  = r & 7;
        int row = (2 * n + (jj >> 3)) * 1024 + cb * 8 + (jj & 7);
        int k = ks * 32 + kb * 8 + e;
        float v = (k < 128) ? Wih0[(size_t)row * 128 + k]
                            : Whh0[(size_t)row * 1024 + (k - 128)];
        w0p[i] = (_Float16)v;
    } else if (gid < N_W1 + N_W0 + N_XH) {
        long long i = gid - N_W1 - N_W0;
        // xh[t][b][d] = x[b][t][d]
        int d = (int)(i & 127);
        int b = (int)((i >> 7) & 255);
        int t = (int)(i >> 15);
        xh[i] = (_Float16)x[((size_t)b * 256 + t) * 128 + d];
    } else if (gid < N_W1 + N_W0 + N_XH + N_H) {
        long long i = gid - N_W1 - N_W0 - N_XH;
        _Float16 v = (_Float16)h0[i];
        bufA[BH + i] = v;   // h_a(-1) parity 1
        bufB[BH + i] = v;   // h_b(-1) parity 1
    }
}

// ---------------------------------------------------------------------------
// Parallel flag-array grid barrier (identical to R9).
__device__ __forceinline__ void gridbar(unsigned* flags, int bid, unsigned target)
{
    __builtin_amdgcn_s_waitcnt(0);     // own write-through stores drained
    __syncthreads();                   // all waves of this block drained
    if (threadIdx.x == 0)
        __hip_atomic_store(flags + bid, target, __ATOMIC_RELAXED,
                           __HIP_MEMORY_SCOPE_AGENT);
    if (threadIdx.x < 256) {
        int guard = 0;
        while (__hip_atomic_load(flags + threadIdx.x, __ATOMIC_RELAXED,
                                 __HIP_MEMORY_SCOPE_AGENT) < target) {
            __builtin_amdgcn_s_sleep(1);
            if (++guard > (1 << 18)) break;        // safety: wrong, not wedged
        }
    }
    __syncthreads();
    if (threadIdx.x < 64)                           // one inv per CU (L1+L2)
        __builtin_amdgcn_fence(__ATOMIC_ACQUIRE, "agent");
    __syncthreads();
}

#define MFMA16(A, Bv, C) __builtin_amdgcn_mfma_f32_16x16x32_f16((A), (Bv), (C), 0, 0, 0)

// ---- chunked prefetch machinery -------------------------------------------
// A chunk = 8 k-steps = 16 half8 fragment registers (64 VGPRs).
// LDCHUNK issues 16 independent 16B loads; MMCHUNK consumes them in 32 MFMAs.
#define LDCHUNK(F_, P_, OFF_) do {                                   \
    _Pragma("unroll")                                                \
    for (int s_ = 0; s_ < 8; ++s_) {                                 \
        F_[2*s_]   = *(const half8*)((P_) + s_*32);                  \
        F_[2*s_+1] = *(const half8*)((P_) + s_*32 + (OFF_));         \
    } } while (0)

#define MMCHUNK(F_) do {                                             \
    _Pragma("unroll")                                                \
    for (int s_ = 0; s_ < 8; ++s_) {                                 \
        half8 b0_ = *(const half8*)(bp);                             \
        half8 b1_ = *(const half8*)(bp + 128);                       \
        acc[0][0] = MFMA16(F_[2*s_],   b0_, acc[0][0]);              \
        acc[0][1] = MFMA16(F_[2*s_],   b1_, acc[0][1]);              \
        acc[1][0] = MFMA16(F_[2*s_+1], b0_, acc[1][0]);              \
        acc[1][1] = MFMA16(F_[2*s_+1], b1_, acc[1][1]);              \
        bp += 1024;                                                  \
    } } while (0)

// 4-step (half) chunk for the xh part of layer 0
#define LDXCHUNK(F_, P_) do {                                        \
    _Pragma("unroll")                                                \
    for (int s_ = 0; s_ < 4; ++s_) {                                 \
        F_[2*s_]   = *(const half8*)((P_) + s_*32);                  \
        F_[2*s_+1] = *(const half8*)((P_) + s_*32 + 16*128);         \
    } } while (0)

#define MMXCHUNK(F_) do {                                            \
    _Pragma("unroll")                                                \
    for (int s_ = 0; s_ < 4; ++s_) {                                 \
        half8 b0_ = *(const half8*)(bp);                             \
        half8 b1_ = *(const half8*)(bp + 128);                       \
        acc[0][0] = MFMA16(F_[2*s_],   b0_, acc[0][0]);              \
        acc[0][1] = MFMA16(F_[2*s_],   b1_, acc[0][1]);              \
        acc[1][0] = MFMA16(F_[2*s_+1], b0_, acc[1][0]);              \
        acc[1][1] = MFMA16(F_[2*s_+1], b1_, acc[1][1]);              \
        bp += 1024;                                                  \
    } } while (0)

__global__ void __launch_bounds__(512)
lstm_main(const _Float16* __restrict__ w1p, const _Float16* __restrict__ w0p,
          const _Float16* __restrict__ xh,
          _Float16* __restrict__ bufA, _Float16* __restrict__ bufB,
          float* __restrict__ hbF,
          const float* __restrict__ c0,
          const float* __restrict__ bih0, const float* __restrict__ bhh0,
          const float* __restrict__ bih1, const float* __restrict__ bhh1,
          const float* __restrict__ Wout, const float* __restrict__ bout,
          float* __restrict__ out, unsigned* __restrict__ sync)
{
    __shared__ _Float16 wlds[65536];   // 128 KiB

    const int tid  = threadIdx.x;
    const int lane = tid & 63;
    const int w    = tid >> 6;           // 0..7
    const int bid  = blockIdx.x;
    const int xcd  = bid & 7;
    const int slot = bid >> 3;           // 0..31
    const int isL1 = ((slot & 1) == 0);  // 16 L1 + 16 L0 blocks per XCD
    const int cb   = xcd * 16 + (slot >> 1);   // 0..127 column-block id
    const int jbase = cb * 8;
    const int jj = lane & 15;
    const int kb = lane >> 4;            // 0..3
    const int jh = jj & 7;
    const int lo = (jj < 8);
    const int rowbase = w * 32;          // wave's 32 batch rows

    // ---- load this block's weights into LDS (once) ----
    {
        const _Float16* src = isL1 ? (w1p + (size_t)cb * 65536)
                                   : (w0p + (size_t)cb * 36864);
        const int nch = isL1 ? 8192 : 4608;   // 16B chunks
        for (int i = tid; i < nch; i += 512)
            *(half8*)&wlds[(size_t)i * 8] = *(const half8*)&src[(size_t)i * 8];
    }
    __syncthreads();

    // ---- biases + cell-state init ----
    const float* bi  = isL1 ? bih1 : bih0;
    const float* bhp = isL1 ? bhh1 : bhh0;
    float bias[4];
#pragma unroll
    for (int g = 0; g < 4; ++g)
        bias[g] = bi[g * 1024 + jbase + jh] + bhp[g * 1024 + jbase + jh];

    float cc[2][4];
#pragma unroll
    for (int mf = 0; mf < 2; ++mf)
#pragma unroll
        for (int r = 0; r < 4; ++r)
            cc[mf][r] = c0[(size_t)(rowbase + mf * 16 + kb * 4 + r) * Hq + jbase + jh];

    floatx4 acc[2][2];
    half8 f0[16], f1[16];                // chunk double buffer (128 VGPRs)

    for (int t = -1; t <= 255; ++t) {
        const int active = isL1 ? (t >= 0) : (t < 255);
        if (active) {
#pragma unroll
            for (int mf = 0; mf < 2; ++mf)
#pragma unroll
                for (int n = 0; n < 2; ++n)
                    acc[mf][n] = (floatx4){0.f, 0.f, 0.f, 0.f};

            const _Float16* bp = wlds + kb * 256 + jj * 8;

            if (isL1) {
                // gates1(t) = h_a(t)@Wih1^T + h_b(t-1)@Whh1^T (64 steps, 8 chunks)
                const _Float16* apA = bufA + (size_t)(t & 1) * BH
                                    + (size_t)(rowbase + jj) * Hq + kb * 8;
                const _Float16* apB = bufB + (size_t)((t + 1) & 1) * BH
                                    + (size_t)(rowbase + jj) * Hq + kb * 8;
                LDCHUNK(f0, apA + 0 * 256, 16 * Hq);
                LDCHUNK(f1, apA + 1 * 256, 16 * Hq);
                MMCHUNK(f0);
                LDCHUNK(f0, apA + 2 * 256, 16 * Hq); MMCHUNK(f1);
                LDCHUNK(f1, apA + 3 * 256, 16 * Hq); MMCHUNK(f0);
                LDCHUNK(f0, apB + 0 * 256, 16 * Hq); MMCHUNK(f1);
                LDCHUNK(f1, apB + 1 * 256, 16 * Hq); MMCHUNK(f0);
                LDCHUNK(f0, apB + 2 * 256, 16 * Hq); MMCHUNK(f1);
                LDCHUNK(f1, apB + 3 * 256, 16 * Hq); MMCHUNK(f0);
                MMCHUNK(f1);
            } else {
                // gates0(t+1) = x(t+1)@Wih0^T + h_a(t)@Whh0^T (36 steps)
                const _Float16* apX = xh + (size_t)(t + 1) * (Bq * 128)
                                    + (size_t)(rowbase + jj) * 128 + kb * 8;
                const _Float16* apA = bufA + (size_t)(t & 1) * BH
                                    + (size_t)(rowbase + jj) * Hq + kb * 8;
                LDXCHUNK(f0, apX);
                LDCHUNK(f1, apA + 0 * 256, 16 * Hq);
                MMXCHUNK(f0);
                LDCHUNK(f0, apA + 1 * 256, 16 * Hq); MMCHUNK(f1);
                LDCHUNK(f1, apA + 2 * 256, 16 * Hq); MMCHUNK(f0);
                LDCHUNK(f0, apA + 3 * 256, 16 * Hq); MMCHUNK(f1);
                MMCHUNK(f0);
            }

            // ---- elementwise: gate-pair exchange + cell update + h store ----
            _Float16* hb = isL1 ? (bufB + (size_t)(t & 1) * BH)
                                : (bufA + (size_t)((t + 1) & 1) * BH);
            unsigned* hb32 = (unsigned*)hb;
#pragma unroll
            for (int mf = 0; mf < 2; ++mf) {
#pragma unroll
                for (int r = 0; r < 4; ++r) {
                    float o0 = acc[mf][0][r];       // lo: i, hi: f
                    float o1 = acc[mf][1][r];       // lo: g, hi: o
                    float p0 = __shfl_xor(o0, 8);
                    float p1 = __shfl_xor(o1, 8);
                    float gi = (lo ? o0 : p0) + bias[0];
                    float gf = (lo ? p0 : o0) + bias[1];
                    float gg = (lo ? o1 : p1) + bias[2];
                    float go = (lo ? p1 : o1) + bias[3];
                    float ii = 1.f / (1.f + expf(-gi));
                    float ff = 1.f / (1.f + expf(-gf));
                    float gt = tanhf(gg);
                    float oo = 1.f / (1.f + expf(-go));
                    float cn = ff * cc[mf][r] + ii * gt;
                    cc[mf][r] = cn;
                    float hn = oo * tanhf(cn);

                    union { _Float16 f; unsigned short u; } cv;
                    cv.f = (_Float16)hn;
                    int prt = __shfl_xor((int)cv.u, 1);   // neighbor j^1's bits
                    int row = rowbase + mf * 16 + kb * 4 + r;
                    if (lo && ((jh & 1) == 0)) {
                        unsigned word = (unsigned)cv.u | ((unsigned)prt << 16);
                        __hip_atomic_store(hb32 + (((size_t)row * Hq + jbase + jh) >> 1),
                                           word, __ATOMIC_RELAXED,
                                           __HIP_MEMORY_SCOPE_AGENT);
                    }
                    if (lo && isL1 && t == 255)
                        __hip_atomic_store(hbF + (size_t)row * Hq + jbase + jh,
                                           hn, __ATOMIC_RELAXED,
                                           __HIP_MEMORY_SCOPE_AGENT);
                }
            }
        }

        gridbar(sync, bid, (unsigned)(t + 2));
    }

    // ---- final: out[b][o] = b_out[o] + sum_k hbF[b][k] * Wout[o][k] ----
    int gid = bid * 512 + tid;
    if (gid < Bq * 128) {
        int b = gid >> 7, o = gid & 127;
        const floatx4* hr = (const floatx4*)(hbF + (size_t)b * Hq);
        const floatx4* wr = (const floatx4*)(Wout + (size_t)o * Hq);
        float s = bout[o];
#pragma unroll 4
        for (int k = 0; k < Hq / 4; ++k) {
            floatx4 hv = hr[k], wv = wr[k];
            s += hv[0] * wv[0] + hv[1] * wv[1] + hv[2] * wv[2] + hv[3] * wv[3];
        }
        out[gid] = s;
    }
}

// ---------------------------------------------------------------------------
extern "C" void kernel_launch(void* const* d_in, const int* in_sizes, int n_in,
                              void* d_out, int out_size, void* d_ws, size_t ws_size,
                              hipStream_t stream)
{
    (void)in_sizes; (void)n_in;
    float* out = (float*)d_out;

    if (ws_size < (size_t)REQ_WS) {
        float v = -(float)(ws_size >> 20);
        hipLaunchKernelGGL(ws_sentinel_kernel, dim3((out_size + 255) / 256), dim3(256),
                           0, stream, out, out_size, v);
        return;
    }

    const float* x    = (const float*)d_in[0];
    const float* h0   = (const float*)d_in[1];
    const float* c0   = (const float*)d_in[2];
    const float* Wih0 = (const float*)d_in[3];
    const float* Whh0 = (const float*)d_in[4];
    const float* bih0 = (const float*)d_in[5];
    const float* bhh0 = (const float*)d_in[6];
    const float* Wih1 = (const float*)d_in[7];
    const float* Whh1 = (const float*)d_in[8];
    const float* bih1 = (const float*)d_in[9];
    const float* bhh1 = (const float*)d_in[10];
    const float* Wout = (const float*)d_in[11];
    const float* bout = (const float*)d_in[12];

    char* ws = (char*)d_ws;
    _Float16* w1p  = (_Float16*)(ws + OFF_W1);
    _Float16* w0p  = (_Float16*)(ws + OFF_W0);
    _Float16* xh   = (_Float16*)(ws + OFF_XH);
    _Float16* bufA = (_Float16*)(ws + OFF_BA);
    _Float16* bufB = (_Float16*)(ws + OFF_BB);
    float*    hbF  = (float*)   (ws + OFF_HF);
    unsigned* sync = (unsigned*)(ws + OFF_SY);

    long long total = N_W1 + N_W0 + N_XH + N_H;   // 21,757,952 = 84992*256
    hipLaunchKernelGGL(prep_kernel, dim3((unsigned)(total / 256)), dim3(256), 0, stream,
                       x, h0, Wih0, Whh0, Wih1, Whh1, w1p, w0p, xh, bufA, bufB, sync);

    hipLaunchKernelGGL(lstm_main, dim3(256), dim3(512), 0, stream,
                       w1p, w0p, xh, bufA, bufB, hbF, c0,
                       bih0, bhh0, bih1, bhh1, Wout, bout, out, sync);
}